// Round 9
// baseline (869.441 us; speedup 1.0000x reference)
//
#include <hip/hip_runtime.h>
#include <hip/hip_bf16.h>
#include <stdint.h>

#define VOCAB 32000
#define HID   256
#define BATCH 16
#define SEQT  256
#define ROWS  (BATCH*SEQT)        // 4096
#define NPAN  (VOCAB/128)         // 250 n-panels
#define MTILES (ROWS/256)         // 16 m-tiles (16 timesteps each)
#define NTILES (MTILES*NPAN)      // 4000 consumer tiles
#define NBLK  256                 // 1 block/CU (LDS 148 KB), all resident

typedef __attribute__((ext_vector_type(8))) short bf16x8_t;
typedef __attribute__((ext_vector_type(4))) float f32x4_t;

__device__ __forceinline__ short f2bs(float x) {
    __hip_bfloat16 h = __float2bfloat16(x);
    return *reinterpret_cast<short*>(&h);
}
__device__ __forceinline__ bf16x8_t cvt8(float4 a, float4 b) {
    union { short s[8]; bf16x8_t v; } u;
    u.s[0] = f2bs(a.x); u.s[1] = f2bs(a.y); u.s[2] = f2bs(a.z); u.s[3] = f2bs(a.w);
    u.s[4] = f2bs(b.x); u.s[5] = f2bs(b.y); u.s[6] = f2bs(b.z); u.s[7] = f2bs(b.w);
    return u.v;
}
__device__ __forceinline__ void barrier_lds() {
    asm volatile("s_waitcnt lgkmcnt(0)\n\ts_barrier" ::: "memory");
}
// tanh via Lambert CF5; clamp handles tails
__device__ __forceinline__ float tanh_cf(float x) {
    float x2 = x * x;
    float nm = x * fmaf(x2, x2 + 105.f, 945.f);
    float dn = fmaf(x2, fmaf(x2, 15.f, 420.f), 945.f);
    float h = nm * __builtin_amdgcn_rcpf(dn);
    return fminf(fmaxf(h, -1.f), 1.f);
}
__device__ __forceinline__ short rne_bf16(float x) {
    uint32_t u = __float_as_uint(x);
    uint32_t r = (u + 0x7FFFu + ((u >> 16) & 1u)) >> 16;
    return (short)r;
}
// 16-B store, write-through to LLC (sc0 sc1): producer-side hs publish path
__device__ __forceinline__ void store_llc16(void* p, bf16x8_t v) {
    asm volatile("global_store_dwordx4 %0, %1, off sc0 sc1" :: "v"(p), "v"(v) : "memory");
}
// 64 B (4x16B) load bypassing L1/L2 (reads LLC): consumer-side hs reads.
// "=&v" EARLY-CLOBBER is load-bearing: outputs must not alias the address
// pair (round-8 fault: %0 overlapped %4, first load clobbered the address).
__device__ __forceinline__ void load_row_llc(const short* p,
                                             bf16x8_t& r0, bf16x8_t& r1,
                                             bf16x8_t& r2, bf16x8_t& r3) {
    asm volatile(
        "global_load_dwordx4 %0, %4, off sc0 sc1\n\t"
        "global_load_dwordx4 %1, %4, off offset:16 sc0 sc1\n\t"
        "global_load_dwordx4 %2, %4, off offset:32 sc0 sc1\n\t"
        "global_load_dwordx4 %3, %4, off offset:48 sc0 sc1\n\t"
        "s_waitcnt vmcnt(0)"
        : "=&v"(r0), "=&v"(r1), "=&v"(r2), "=&v"(r3)
        : "v"(p) : "memory");
}

// ---------------------------------------------------------------------------
// K1: xp[t][h][b] = Wih[inputs[b][t]][h]+bih[h]+bhh[h] (b inner). Also zeroes
// S + ctrl, converts Wfc -> bf16.
// ---------------------------------------------------------------------------
__global__ __launch_bounds__(256) void xproj_kernel(
    const int* __restrict__ inputs,
    const float* __restrict__ Wih,
    const float* __restrict__ bih,
    const float* __restrict__ bhh,
    const float* __restrict__ Wfc,
    float* __restrict__ xp,            // [T][H][B]
    float* __restrict__ S,
    unsigned* __restrict__ ctrl,
    __hip_bfloat16* __restrict__ Wfcb,
    int do_cvt)
{
    const int tid = threadIdx.x, blk = blockIdx.x;
    const int t = blk >> 4, hb = (blk & 15) << 4;
    const int b = tid & 15, h = hb + (tid >> 4);
    const int id = inputs[b * SEQT + t];
    xp[(t * HID + h) * BATCH + b] = Wih[(size_t)id * HID + h] + bih[h] + bhh[h];
    const int idx = blk * 256 + tid;
    if (idx < ROWS) S[idx] = 0.f;
    if (idx < 4) ctrl[idx] = 0u;
    if (do_cvt && idx < (VOCAB * HID / 8)) {
        const float4* p = (const float4*)(Wfc + (size_t)idx * 8);
        *(bf16x8_t*)((short*)Wfcb + (size_t)idx * 8) = cvt8(p[0], p[1]);
    }
}

// ---------------------------------------------------------------------------
// K2: FUSED persistent producer/consumer, LLC-mediated (NO acquire/release
// cache maintenance — round 7 showed agent-scope acquires thrash every L2).
// 256 blocks x 512 thr, 148 KB LDS -> 1 block/CU. Ticket 0 runs the RNN:
// hs stores write-through to LLC (sc0 sc1), progress published via atomicMax
// (RMW, LLC-coherent). Consumers poll via RMW atomicAdd and read hs ONLY
// through sc0|sc1 loads (bypass L1/L2 -> always fresh, zero invalidates).
// Consumer A-tile (256x256) loaded once per tile into a full-K LDS buffer;
// B (Wfcb) uses the normal cached path and stays hot in L2.
// ---------------------------------------------------------------------------
template <bool BF16B>
__global__ __launch_bounds__(512, 1) void fused_kernel(
    const float* __restrict__ xp,      // [T][H][B] fp32, biases folded
    const float* __restrict__ Whh,
    __hip_bfloat16* __restrict__ hs,   // [T][B][H] bf16 (LLC-resident copy)
    const void* __restrict__ WfcP,
    const float* __restrict__ bfc,
    const int* __restrict__ targets,
    float* __restrict__ S,
    float* __restrict__ TL,
    unsigned* __restrict__ ctrl)       // [0]=ticket [1]=progress [2]=queue
{
    __shared__ char smem[148480];      // As 128K | Bs 16K | tgt 1K (>80K -> 1 blk/CU)
    short* As  = (short*)smem;                     // slot ((s*4+ks)*256+m)*8
    short* Bs  = (short*)(smem + 131072);          // [buf][(ks*128+row)*8]
    int*   tgt = (int*)(smem + 147456);
    auto   hbuf = (short (*)[16][264])smem;        // producer alias (34 KB)
    __shared__ unsigned role, sh_tile;

    const int tid = threadIdx.x;
    if (tid == 0) role = atomicAdd(&ctrl[0], 1u);
    __syncthreads();
    const unsigned my_role = role;

    const int l = tid & 63, w = tid >> 6;
    const int lr = l & 15, lh = l >> 4;

    if (my_role == 0) {
        // ================= PRODUCER: RNN recurrence =================
        const int cm = tid >> 5;            // copy row 0..15
        const int cc = (tid & 31) * 8;      // copy col x8 shorts
        const int n0_ = w * 32 + lr, n1_ = n0_ + 16;

        bf16x8_t bfrag[2][8];               // B[k][n]=Whh[n][k]
#pragma unroll
        for (int nt = 0; nt < 2; nt++) {
            int n = nt ? n1_ : n0_;
#pragma unroll
            for (int ki = 0; ki < 8; ki++) {
                const float4* p = (const float4*)(Whh + n * HID + ki * 32 + lh * 8);
                bfrag[nt][ki] = cvt8(p[0], p[1]);
            }
        }
        for (int i = tid; i < 16 * 264; i += 512) ((short*)hbuf[0])[i] = 0;
        __syncthreads();

        float4 xv0 = *(const float4*)(xp + (size_t)n0_ * BATCH + lh * 4);
        float4 xv1 = *(const float4*)(xp + (size_t)n1_ * BATCH + lh * 4);

        int cur = 0;
        for (int t = 0; t < SEQT; t++) {
            if (t > 0) {   // pipelined LDS->LLC copy of h_{t-1}
                bf16x8_t hv = *(const bf16x8_t*)(&hbuf[cur][cm][cc]);
                store_llc16((short*)hs + (size_t)(t - 1) * BATCH * HID + cm * HID + cc, hv);
                if ((t & 7) == 0) {   // publish P=t (h_{0..t-1} at LLC)
                    asm volatile("s_waitcnt vmcnt(0)" ::: "memory");
                    __syncthreads();
                    if (tid == 0) atomicMax(&ctrl[1], (unsigned)t);
                }
            }

            bf16x8_t afr[8];   // A[m=lr][k=ki*32+lh*8+j]
#pragma unroll
            for (int ki = 0; ki < 8; ki++)
                afr[ki] = *(const bf16x8_t*)(&hbuf[cur][lr][ki * 32 + lh * 8]);

            f32x4_t a0a = {xv0.x, xv0.y, xv0.z, xv0.w}, a0b = {0, 0, 0, 0};
            f32x4_t a1a = {xv1.x, xv1.y, xv1.z, xv1.w}, a1b = {0, 0, 0, 0};
#pragma unroll
            for (int ki = 0; ki < 4; ki++) {
                a0a = __builtin_amdgcn_mfma_f32_16x16x32_bf16(afr[ki],     bfrag[0][ki],     a0a, 0, 0, 0);
                a0b = __builtin_amdgcn_mfma_f32_16x16x32_bf16(afr[ki + 4], bfrag[0][ki + 4], a0b, 0, 0, 0);
                a1a = __builtin_amdgcn_mfma_f32_16x16x32_bf16(afr[ki],     bfrag[1][ki],     a1a, 0, 0, 0);
                a1b = __builtin_amdgcn_mfma_f32_16x16x32_bf16(afr[ki + 4], bfrag[1][ki + 4], a1b, 0, 0, 0);
            }

            float4 xn0 = {0,0,0,0}, xn1 = {0,0,0,0};
            if (t + 1 < SEQT) {
                const float* xb = xp + (size_t)(t + 1) * HID * BATCH + lh * 4;
                xn0 = *(const float4*)(xb + (size_t)n0_ * BATCH);
                xn1 = *(const float4*)(xb + (size_t)n1_ * BATCH);
            }

            // C/D: col = lane&15, row = (lane>>4)*4 + reg
#pragma unroll
            for (int r = 0; r < 4; r++) {
                hbuf[cur ^ 1][lh * 4 + r][n0_] = rne_bf16(tanh_cf(a0a[r] + a0b[r]));
                hbuf[cur ^ 1][lh * 4 + r][n1_] = rne_bf16(tanh_cf(a1a[r] + a1b[r]));
            }
            xv0 = xn0; xv1 = xn1;
            cur ^= 1;
            barrier_lds();
        }
        {   // final copy h_{255} + publish P=256
            bf16x8_t hv = *(const bf16x8_t*)(&hbuf[cur][cm][cc]);
            store_llc16((short*)hs + (size_t)(SEQT - 1) * BATCH * HID + cm * HID + cc, hv);
            asm volatile("s_waitcnt vmcnt(0)" ::: "memory");
            __syncthreads();
            if (tid == 0) atomicMax(&ctrl[1], (unsigned)SEQT);
        }
        return;   // producer's LDS layout differs; don't join consumption
    }

    // ================= CONSUMER LOOP: persistent, queue-fed ================
    const int wm = (w >> 1) * 64, wn = (w & 1) * 64;   // 4x2 waves of 64x64
    const int brow = tid & 127, bsub = tid >> 7;
    const int am = tid & 255, ash = (tid >> 8) * 4;    // A-fill: row, slab-half
    unsigned seen = 0;

    for (;;) {
        __syncthreads();                               // LDS reuse safety
        if (tid == 0) sh_tile = atomicAdd(&ctrl[2], 1u);
        __syncthreads();
        const unsigned tile = sh_tile;
        if (tile >= NTILES) break;
        const int mt_ = tile / NPAN, nt_ = tile % NPAN;
        const int m0 = mt_ * 256, n0g = nt_ * 128;

        if (tid < 256) {                               // r = t*16+b
            int r = m0 + tid;
            tgt[tid] = targets[((r & 15) << 8) | (r >> 4)];
        }
        if (tid == 0) {
            const unsigned need = (unsigned)((mt_ + 1) * 16);
            if (seen < need) {
                unsigned p;
                while ((p = atomicAdd(&ctrl[1], 0u)) < need)   // LLC RMW poll
                    __builtin_amdgcn_s_sleep(32);
                seen = p;
            }
        }
        __syncthreads();   // progress reached; hs rows are at LLC

        // ---- A fill: 256x256 bf16 tile -> LDS (sc0|sc1 loads from LLC) ----
        {
            const short* gp = (const short*)hs + (size_t)(m0 + am) * HID + ash * 32;
#pragma unroll
            for (int s2 = 0; s2 < 4; s2++) {
                bf16x8_t r0, r1, r2, r3;
                load_row_llc(gp + s2 * 32, r0, r1, r2, r3);
                const int s = ash + s2;
                *(bf16x8_t*)&As[(((s * 4 + 0) * 256) + am) * 8] = r0;
                *(bf16x8_t*)&As[(((s * 4 + 1) * 256) + am) * 8] = r1;
                *(bf16x8_t*)&As[(((s * 4 + 2) * 256) + am) * 8] = r2;
                *(bf16x8_t*)&As[(((s * 4 + 3) * 256) + am) * 8] = r3;
            }
        }

        const __hip_bfloat16* gBb = (const __hip_bfloat16*)WfcP + (size_t)(n0g + brow) * HID + bsub * 8;
        const float*          gBf = (const float*)WfcP + (size_t)(n0g + brow) * HID + bsub * 8;

        f32x4_t acc[4][4];
        const f32x4_t z = {0.f, 0.f, 0.f, 0.f};
#pragma unroll
        for (int i = 0; i < 4; i++)
#pragma unroll
            for (int j = 0; j < 4; j++) acc[i][j] = z;

        // B slab 0 -> Bs[0]; prefetch slab 1 (normal cached loads)
        bf16x8_t pB[2]; float4 pF0[2], pF1[2];
        if (BF16B) {
            pB[0] = *(const bf16x8_t*)(gBb);
            *(bf16x8_t*)&Bs[(bsub * 128 + brow) * 8] = pB[0];
            pB[1] = *(const bf16x8_t*)(gBb + 32);
        } else {
            pF0[0] = ((const float4*)gBf)[0]; pF1[0] = ((const float4*)gBf)[1];
            *(bf16x8_t*)&Bs[(bsub * 128 + brow) * 8] = cvt8(pF0[0], pF1[0]);
            pF0[1] = ((const float4*)(gBf + 32))[0]; pF1[1] = ((const float4*)(gBf + 32))[1];
        }
        __syncthreads();   // A fill + B slab0 visible

#pragma unroll
        for (int s = 0; s < 8; s++) {
            const int buf = s & 1;
            bf16x8_t a[4], b[4];
#pragma unroll
            for (int mt = 0; mt < 4; mt++)
                a[mt] = *(const bf16x8_t*)&As[(((s * 4 + lh) * 256) + wm + mt * 16 + lr) * 8];
#pragma unroll
            for (int nt = 0; nt < 4; nt++)
                b[nt] = *(const bf16x8_t*)&Bs[(buf * 4096) + (lh * 128 + wn + nt * 16 + lr) * 8];

            if (s + 1 < 8) {   // stage prefetched B slab s+1
                const int sl = (s + 1) & 1;
                if (BF16B) *(bf16x8_t*)&Bs[((buf ^ 1) * 4096) + (bsub * 128 + brow) * 8] = pB[sl];
                else       *(bf16x8_t*)&Bs[((buf ^ 1) * 4096) + (bsub * 128 + brow) * 8] = cvt8(pF0[sl], pF1[sl]);
            }
            if (s + 2 < 8) {   // 2-deep B global prefetch
                const int k0 = (s + 2) * 32, sl = s & 1;
                if (BF16B) pB[sl] = *(const bf16x8_t*)(gBb + k0);
                else { pF0[sl] = ((const float4*)(gBf + k0))[0]; pF1[sl] = ((const float4*)(gBf + k0))[1]; }
            }
#pragma unroll
            for (int mt = 0; mt < 4; mt++)
#pragma unroll
                for (int nt = 0; nt < 4; nt++)
                    acc[mt][nt] = __builtin_amdgcn_mfma_f32_16x16x32_bf16(a[mt], b[nt], acc[mt][nt], 0, 0, 0);
            barrier_lds();
        }

        // epilogue: bias + exp + rowsum; target logits inline
        int tg[16];
#pragma unroll
        for (int i = 0; i < 16; i++)
            tg[i] = tgt[wm + (i >> 2) * 16 + lh * 4 + (i & 3)];

        float rsum[16];
#pragma unroll
        for (int i = 0; i < 16; i++) rsum[i] = 0.f;
#pragma unroll
        for (int nt = 0; nt < 4; nt++) {
            int n = n0g + wn + nt * 16 + lr;
            float bias = bfc[n];
#pragma unroll
            for (int mt = 0; mt < 4; mt++)
#pragma unroll
                for (int r = 0; r < 4; r++) {
                    float v = acc[mt][nt][r] + bias;
                    rsum[mt * 4 + r] += __expf(v);
                    if (tg[mt * 4 + r] == n)
                        TL[m0 + wm + mt * 16 + lh * 4 + r] = v;
                }
        }
#pragma unroll
        for (int m = 1; m < 16; m <<= 1)
#pragma unroll
            for (int i = 0; i < 16; i++) rsum[i] += __shfl_xor(rsum[i], m, 64);
        if (lr == 0) {
#pragma unroll
            for (int i = 0; i < 16; i++) {
                int r = m0 + wm + (i >> 2) * 16 + lh * 4 + (i & 3);
                atomicAdd(&S[r], rsum[i]);
            }
        }
    }
}

// ---------------------------------------------------------------------------
// K3: loss = mean_r( log(S[r]) - TL[r] )
// ---------------------------------------------------------------------------
__global__ __launch_bounds__(256) void loss_kernel(
    const float* __restrict__ S,
    const float* __restrict__ TL,
    float* __restrict__ out)
{
    int tid = threadIdx.x;
    float p = 0.f;
    for (int i = tid; i < ROWS; i += 256) p += __logf(S[i]) - TL[i];
#pragma unroll
    for (int m = 1; m < 64; m <<= 1) p += __shfl_xor(p, m, 64);
    __shared__ float red[4];
    if ((tid & 63) == 0) red[tid >> 6] = p;
    __syncthreads();
    if (tid == 0)
        out[0] = (red[0] + red[1] + red[2] + red[3]) / (float)ROWS;
}

extern "C" void kernel_launch(void* const* d_in, const int* in_sizes, int n_in,
                              void* d_out, int out_size, void* d_ws, size_t ws_size,
                              hipStream_t stream)
{
    (void)in_sizes; (void)n_in; (void)out_size;
    const int*   inputs  = (const int*)d_in[0];
    const int*   targets = (const int*)d_in[1];
    const float* Wih = (const float*)d_in[2];
    const float* bih = (const float*)d_in[3];
    const float* Whh = (const float*)d_in[4];
    const float* bhh = (const float*)d_in[5];
    const float* Wfc = (const float*)d_in[6];
    const float* bfc = (const float*)d_in[7];

    float*    S    = (float*)d_ws;                         // 4096 f32
    float*    TL   = S + ROWS;                             // 4096 f32
    unsigned* ctrl = (unsigned*)(TL + ROWS);               // ticket/prog/queue
    float*    xp   = (float*)(ctrl + 64);                  // [T][H][B] fp32, 4 MB
    __hip_bfloat16* hs = (__hip_bfloat16*)(xp + (size_t)SEQT * HID * BATCH); // 2 MB
    __hip_bfloat16* Wfcb = hs + (size_t)ROWS * HID;        // 16 MB

    const size_t need = (size_t)(2 * ROWS) * 4 + 256 + (size_t)SEQT * HID * BATCH * 4
                      + (size_t)ROWS * HID * 2 + (size_t)VOCAB * HID * 2;
    const int use_bf16b = (ws_size >= need) ? 1 : 0;

    xproj_kernel<<<SEQT * 16, 256, 0, stream>>>(
        inputs, Wih, bih, bhh, Wfc, xp, S, ctrl, Wfcb, use_bf16b);
    if (use_bf16b)
        fused_kernel<true><<<NBLK, 512, 0, stream>>>(
            xp, Whh, hs, (const void*)Wfcb, bfc, targets, S, TL, ctrl);
    else
        fused_kernel<false><<<NBLK, 512, 0, stream>>>(
            xp, Whh, hs, (const void*)Wfc, bfc, targets, S, TL, ctrl);
    loss_kernel<<<1, 256, 0, stream>>>(S, TL, (float*)d_out);
}

// Round 10
// 554.255 us; speedup vs baseline: 1.5687x; 1.5687x over previous
//
#include <hip/hip_runtime.h>
#include <hip/hip_bf16.h>
#include <stdint.h>

#define VOCAB 32000
#define HID   256
#define BATCH 16
#define SEQT  256
#define ROWS  (BATCH*SEQT)        // 4096
#define NPAN  (VOCAB/128)         // 250 n-panels
#define MTILES (ROWS/256)         // 16 m-tiles
#define FCBLK (NPAN*MTILES)       // 4000 fc blocks

typedef __attribute__((ext_vector_type(8))) short bf16x8_t;
typedef __attribute__((ext_vector_type(4))) float f32x4_t;

__device__ __forceinline__ short f2bs(float x) {
    __hip_bfloat16 h = __float2bfloat16(x);
    return *reinterpret_cast<short*>(&h);
}
__device__ __forceinline__ bf16x8_t cvt8(float4 a, float4 b) {
    union { short s[8]; bf16x8_t v; } u;
    u.s[0] = f2bs(a.x); u.s[1] = f2bs(a.y); u.s[2] = f2bs(a.z); u.s[3] = f2bs(a.w);
    u.s[4] = f2bs(b.x); u.s[5] = f2bs(b.y); u.s[6] = f2bs(b.z); u.s[7] = f2bs(b.w);
    return u.v;
}
__device__ __forceinline__ void barrier_lds() {
    asm volatile("s_waitcnt lgkmcnt(0)\n\ts_barrier" ::: "memory");
}
// tanh via Lambert CF5: |err|<1.2e-3 for |x|<3.5; clamp handles tails
__device__ __forceinline__ float tanh_cf(float x) {
    float x2 = x * x;
    float nm = x * fmaf(x2, x2 + 105.f, 945.f);
    float dn = fmaf(x2, fmaf(x2, 15.f, 420.f), 945.f);
    float h = nm * __builtin_amdgcn_rcpf(dn);
    return fminf(fmaxf(h, -1.f), 1.f);
}
__device__ __forceinline__ short rne_bf16(float x) {
    uint32_t u = __float_as_uint(x);
    uint32_t r = (u + 0x7FFFu + ((u >> 16) & 1u)) >> 16;
    return (short)r;
}

// ---------------------------------------------------------------------------
// K1: xp[t][h][b] = Wih[inputs[b][t]][h]+bih[h]+bhh[h] (b inner -> rnn loads
// x as dwordx4). Also zeroes S, converts Wfc -> bf16 (Wfcb).
// ---------------------------------------------------------------------------
__global__ __launch_bounds__(256) void xproj_kernel(
    const int* __restrict__ inputs,
    const float* __restrict__ Wih,
    const float* __restrict__ bih,
    const float* __restrict__ bhh,
    const float* __restrict__ Wfc,
    float* __restrict__ xp,            // [T][H][B]
    float* __restrict__ S,
    __hip_bfloat16* __restrict__ Wfcb,
    int do_cvt)
{
    const int tid = threadIdx.x, blk = blockIdx.x;
    const int t = blk >> 4, hb = (blk & 15) << 4;
    const int b = tid & 15, h = hb + (tid >> 4);
    const int id = inputs[b * SEQT + t];
    xp[(t * HID + h) * BATCH + b] = Wih[(size_t)id * HID + h] + bih[h] + bhh[h];
    const int idx = blk * 256 + tid;
    if (idx < ROWS) S[idx] = 0.f;
    if (do_cvt && idx < (VOCAB * HID / 8)) {
        const float4* p = (const float4*)(Wfc + (size_t)idx * 8);
        *(bf16x8_t*)((short*)Wfcb + (size_t)idx * 8) = cvt8(p[0], p[1]);
    }
}

// ---------------------------------------------------------------------------
// K2: RNN recurrence, standalone (fusion abandoned: rounds 6-9 showed the
// producer stalls ~4x when 250 blocks hammer its LLC slices). One block,
// 512 threads. Whh bf16 B-frags in regs; h double-buffered in LDS; x folded
// into the MFMA C operand (no epilogue add); one lgkm-only barrier/step.
// ---------------------------------------------------------------------------
__global__ __launch_bounds__(512, 1) void rnn_kernel(
    const float* __restrict__ xp,      // [T][H][B] fp32, biases folded
    const float* __restrict__ Whh,
    __hip_bfloat16* __restrict__ hs)   // [T][B][H] bf16
{
    __shared__ short hbuf[2][16][264];     // +8 pad
    const int tid = threadIdx.x;
    const int l = tid & 63, w = tid >> 6;
    const int lr = l & 15, lh = l >> 4;
    const int cm = tid >> 5;               // h-copy: row 0..15
    const int cc = (tid & 31) * 8;         // h-copy: col x8 shorts
    const int n0_ = w * 32 + lr, n1_ = n0_ + 16;

    bf16x8_t bfrag[2][8];                  // B[k][n]=Whh[n][k]
#pragma unroll
    for (int nt = 0; nt < 2; nt++) {
        int n = nt ? n1_ : n0_;
#pragma unroll
        for (int ki = 0; ki < 8; ki++) {
            const float4* p = (const float4*)(Whh + n * HID + ki * 32 + lh * 8);
            bfrag[nt][ki] = cvt8(p[0], p[1]);
        }
    }
    for (int i = tid; i < 16 * 264; i += 512) ((short*)hbuf[0])[i] = 0;
    __syncthreads();

    // x for t=0: rows lh*4..+3 contiguous (transposed xp)
    float4 xv0 = *(const float4*)(xp + (size_t)n0_ * BATCH + lh * 4);
    float4 xv1 = *(const float4*)(xp + (size_t)n1_ * BATCH + lh * 4);

    int cur = 0;
    for (int t = 0; t < SEQT; t++) {
        if (t > 0) {   // pipelined LDS->global copy of h_{t-1}
            bf16x8_t hv = *(const bf16x8_t*)(&hbuf[cur][cm][cc]);
            *(bf16x8_t*)((short*)hs + (size_t)(t - 1) * BATCH * HID + cm * HID + cc) = hv;
        }

        bf16x8_t afr[8];   // A[m=lr][k=ki*32+lh*8+j]
#pragma unroll
        for (int ki = 0; ki < 8; ki++)
            afr[ki] = *(const bf16x8_t*)(&hbuf[cur][lr][ki * 32 + lh * 8]);

        // acc initialized with x (C operand) -> no epilogue add
        f32x4_t a0a = {xv0.x, xv0.y, xv0.z, xv0.w}, a0b = {0, 0, 0, 0};
        f32x4_t a1a = {xv1.x, xv1.y, xv1.z, xv1.w}, a1b = {0, 0, 0, 0};
#pragma unroll
        for (int ki = 0; ki < 4; ki++) {
            a0a = __builtin_amdgcn_mfma_f32_16x16x32_bf16(afr[ki],     bfrag[0][ki],     a0a, 0, 0, 0);
            a0b = __builtin_amdgcn_mfma_f32_16x16x32_bf16(afr[ki + 4], bfrag[0][ki + 4], a0b, 0, 0, 0);
            a1a = __builtin_amdgcn_mfma_f32_16x16x32_bf16(afr[ki],     bfrag[1][ki],     a1a, 0, 0, 0);
            a1b = __builtin_amdgcn_mfma_f32_16x16x32_bf16(afr[ki + 4], bfrag[1][ki + 4], a1b, 0, 0, 0);
        }

        float4 xn0 = {0,0,0,0}, xn1 = {0,0,0,0};
        if (t + 1 < SEQT) {
            const float* xb = xp + (size_t)(t + 1) * HID * BATCH + lh * 4;
            xn0 = *(const float4*)(xb + (size_t)n0_ * BATCH);
            xn1 = *(const float4*)(xb + (size_t)n1_ * BATCH);
        }

        // C/D: col = lane&15, row = (lane>>4)*4 + reg
#pragma unroll
        for (int r = 0; r < 4; r++) {
            hbuf[cur ^ 1][lh * 4 + r][n0_] = rne_bf16(tanh_cf(a0a[r] + a0b[r]));
            hbuf[cur ^ 1][lh * 4 + r][n1_] = rne_bf16(tanh_cf(a1a[r] + a1b[r]));
        }
        xv0 = xn0; xv1 = xn1;
        cur ^= 1;
        barrier_lds();
    }
    bf16x8_t hv = *(const bf16x8_t*)(&hbuf[cur][cm][cc]);
    *(bf16x8_t*)((short*)hs + (size_t)(SEQT - 1) * BATCH * HID + cm * HID + cc) = hv;
}

// ---------------------------------------------------------------------------
// K3: FC GEMM + exp-rowsum + target-logit. 4000 blocks x 512 thr, tile
// 256m x 128n, K=256 in 8 slabs of 32. Double-buffered LDS (48 KB -> 2
// blocks/CU), register prefetch, one lgkm-only barrier per slab. m-major
// block order: 250 consecutive blocks share the A slab (128 KB, L2-hot).
// |logit| <= ~16.1 -> fp32 exp needs no max subtraction.
// ---------------------------------------------------------------------------
template <bool BF16B>
__global__ __launch_bounds__(512, 4) void fc_kernel(
    const __hip_bfloat16* __restrict__ hs,
    const void* __restrict__ WfcP,
    const float* __restrict__ bfc,
    const int* __restrict__ targets,
    float* __restrict__ S,
    float* __restrict__ TL)
{
    __shared__ short As[2][4 * 256 * 8];   // 2 x 16 KB
    __shared__ short Bs[2][4 * 128 * 8];   // 2 x 8 KB
    __shared__ int   tgt[256];

    const int bid = blockIdx.x;
    const int m_id = bid / NPAN, n_id = bid % NPAN;   // m-major: A L2 reuse
    const int m0 = m_id * 256, n0g = n_id * 128;

    const int tid = threadIdx.x;
    const int l = tid & 63, w = tid >> 6;
    const int lr = l & 15, lh = l >> 4;
    const int wm = (w >> 1) * 64, wn = (w & 1) * 64;  // 4x2 waves of 64x64
    const int arow = tid & 255, asub = tid >> 8;      // A: chunks asub, asub+2
    const int brow = tid & 127, bsub = tid >> 7;      // B: chunk bsub

    if (tid < 256) {                                  // r = t*16+b
        int r = m0 + tid;
        tgt[tid] = targets[((r & 15) << 8) | (r >> 4)];
    }

    const __hip_bfloat16* gA = hs + (size_t)(m0 + arow) * HID + asub * 8;
    const __hip_bfloat16* gBb = (const __hip_bfloat16*)WfcP + (size_t)(n0g + brow) * HID + bsub * 8;
    const float*          gBf = (const float*)WfcP + (size_t)(n0g + brow) * HID + bsub * 8;

    f32x4_t acc[4][4];
    const f32x4_t z = {0.f, 0.f, 0.f, 0.f};
#pragma unroll
    for (int i = 0; i < 4; i++)
#pragma unroll
        for (int j = 0; j < 4; j++) acc[i][j] = z;

    bf16x8_t pA0[2], pA1[2], pB[2];
    float4 pF0[2], pF1[2];
    // slab 0 -> LDS[0]
    pA0[0] = *(const bf16x8_t*)(gA);
    pA1[0] = *(const bf16x8_t*)(gA + 16);
    *(bf16x8_t*)&As[0][(asub * 256 + arow) * 8] = pA0[0];
    *(bf16x8_t*)&As[0][((asub + 2) * 256 + arow) * 8] = pA1[0];
    if (BF16B) {
        pB[0] = *(const bf16x8_t*)(gBb);
        *(bf16x8_t*)&Bs[0][(bsub * 128 + brow) * 8] = pB[0];
    } else {
        pF0[0] = ((const float4*)gBf)[0]; pF1[0] = ((const float4*)gBf)[1];
        *(bf16x8_t*)&Bs[0][(bsub * 128 + brow) * 8] = cvt8(pF0[0], pF1[0]);
    }
    // prefetch slab 1
    pA0[1] = *(const bf16x8_t*)(gA + 32);
    pA1[1] = *(const bf16x8_t*)(gA + 48);
    if (BF16B) pB[1] = *(const bf16x8_t*)(gBb + 32);
    else { pF0[1] = ((const float4*)(gBf + 32))[0]; pF1[1] = ((const float4*)(gBf + 32))[1]; }
    __syncthreads();

#pragma unroll
    for (int s = 0; s < 8; s++) {
        const int buf = s & 1;
        bf16x8_t a[4], b[4];
#pragma unroll
        for (int mt = 0; mt < 4; mt++)
            a[mt] = *(const bf16x8_t*)&As[buf][(lh * 256 + wm + mt * 16 + lr) * 8];
#pragma unroll
        for (int nt = 0; nt < 4; nt++)
            b[nt] = *(const bf16x8_t*)&Bs[buf][(lh * 128 + wn + nt * 16 + lr) * 8];

        if (s + 1 < 8) {   // stage prefetched regs into the other buffer
            const int sl = (s + 1) & 1;
            *(bf16x8_t*)&As[buf ^ 1][(asub * 256 + arow) * 8] = pA0[sl];
            *(bf16x8_t*)&As[buf ^ 1][((asub + 2) * 256 + arow) * 8] = pA1[sl];
            if (BF16B) *(bf16x8_t*)&Bs[buf ^ 1][(bsub * 128 + brow) * 8] = pB[sl];
            else       *(bf16x8_t*)&Bs[buf ^ 1][(bsub * 128 + brow) * 8] = cvt8(pF0[sl], pF1[sl]);
        }
        if (s + 2 < 8) {   // 2-deep global prefetch
            const int k0 = (s + 2) * 32, sl = s & 1;
            pA0[sl] = *(const bf16x8_t*)(gA + k0);
            pA1[sl] = *(const bf16x8_t*)(gA + k0 + 16);
            if (BF16B) pB[sl] = *(const bf16x8_t*)(gBb + k0);
            else { pF0[sl] = ((const float4*)(gBf + k0))[0]; pF1[sl] = ((const float4*)(gBf + k0))[1]; }
        }
#pragma unroll
        for (int mt = 0; mt < 4; mt++)
#pragma unroll
            for (int nt = 0; nt < 4; nt++)
                acc[mt][nt] = __builtin_amdgcn_mfma_f32_16x16x32_bf16(a[mt], b[nt], acc[mt][nt], 0, 0, 0);
        barrier_lds();
    }

    // epilogue: bias + exp + rowsum; target logits inline
    int tg[16];
#pragma unroll
    for (int i = 0; i < 16; i++)
        tg[i] = tgt[wm + (i >> 2) * 16 + lh * 4 + (i & 3)];

    float rsum[16];
#pragma unroll
    for (int i = 0; i < 16; i++) rsum[i] = 0.f;
#pragma unroll
    for (int nt = 0; nt < 4; nt++) {
        int n = n0g + wn + nt * 16 + lr;
        float bias = bfc[n];
#pragma unroll
        for (int mt = 0; mt < 4; mt++)
#pragma unroll
            for (int r = 0; r < 4; r++) {
                float v = acc[mt][nt][r] + bias;
                rsum[mt * 4 + r] += __expf(v);
                if (tg[mt * 4 + r] == n)
                    TL[m0 + wm + mt * 16 + lh * 4 + r] = v;
            }
    }
#pragma unroll
    for (int m = 1; m < 16; m <<= 1)
#pragma unroll
        for (int i = 0; i < 16; i++) rsum[i] += __shfl_xor(rsum[i], m, 64);
    if (lr == 0) {
#pragma unroll
        for (int i = 0; i < 16; i++) {
            int r = m0 + wm + (i >> 2) * 16 + lh * 4 + (i & 3);
            atomicAdd(&S[r], rsum[i]);
        }
    }
}

// ---------------------------------------------------------------------------
// K4: loss = mean_r( log(S[r]) - TL[r] )
// ---------------------------------------------------------------------------
__global__ __launch_bounds__(256) void loss_kernel(
    const float* __restrict__ S,
    const float* __restrict__ TL,
    float* __restrict__ out)
{
    int tid = threadIdx.x;
    float p = 0.f;
    for (int i = tid; i < ROWS; i += 256) p += __logf(S[i]) - TL[i];
#pragma unroll
    for (int m = 1; m < 64; m <<= 1) p += __shfl_xor(p, m, 64);
    __shared__ float red[4];
    if ((tid & 63) == 0) red[tid >> 6] = p;
    __syncthreads();
    if (tid == 0)
        out[0] = (red[0] + red[1] + red[2] + red[3]) / (float)ROWS;
}

extern "C" void kernel_launch(void* const* d_in, const int* in_sizes, int n_in,
                              void* d_out, int out_size, void* d_ws, size_t ws_size,
                              hipStream_t stream)
{
    (void)in_sizes; (void)n_in; (void)out_size;
    const int*   inputs  = (const int*)d_in[0];
    const int*   targets = (const int*)d_in[1];
    const float* Wih = (const float*)d_in[2];
    const float* bih = (const float*)d_in[3];
    const float* Whh = (const float*)d_in[4];
    const float* bhh = (const float*)d_in[5];
    const float* Wfc = (const float*)d_in[6];
    const float* bfc = (const float*)d_in[7];

    float* S  = (float*)d_ws;                              // 4096 f32
    float* TL = S + ROWS;                                  // 4096 f32
    float* xp = TL + ROWS;                                 // [T][H][B] fp32, 4 MB
    __hip_bfloat16* hs = (__hip_bfloat16*)(xp + (size_t)SEQT * HID * BATCH); // 2 MB
    __hip_bfloat16* Wfcb = hs + (size_t)ROWS * HID;        // 16 MB

    const size_t need = (size_t)(2 * ROWS) * 4 + (size_t)SEQT * HID * BATCH * 4
                      + (size_t)ROWS * HID * 2 + (size_t)VOCAB * HID * 2;
    const int use_bf16b = (ws_size >= need) ? 1 : 0;

    xproj_kernel<<<SEQT * 16, 256, 0, stream>>>(
        inputs, Wih, bih, bhh, Wfc, xp, S, Wfcb, use_bf16b);
    rnn_kernel<<<1, 512, 0, stream>>>(xp, Whh, hs);
    if (use_bf16b)
        fc_kernel<true><<<FCBLK, 512, 0, stream>>>(hs, (const void*)Wfcb, bfc, targets, S, TL);
    else
        fc_kernel<false><<<FCBLK, 512, 0, stream>>>(hs, (const void*)Wfc, bfc, targets, S, TL);
    loss_kernel<<<1, 256, 0, stream>>>(S, TL, (float*)d_out);
}